// Round 1
// baseline (244.117 us; speedup 1.0000x reference)
//
#include <hip/hip_runtime.h>

// Problem constants (B=8, C=512, H=W=64, K=19 classes)
#define NCLS   19
#define NB     8
#define NC     512
#define NHW    4096      // 64*64
#define EPSM   1e-6f     // mean denominator eps
#define EPSC   1e-8f     // cosine eps

// Workspace layout (bytes), all offsets 256-aligned
#define OFF_LABELS   0u          // int32 [NB*NHW]            131072 B
#define OFF_COUNTS   131072u     // float [NB*NCLS]           608 B (padded 1024)
#define OFF_SUMS_S   132096u     // float [NB*NC*NCLS]        311296 B (becomes means in place)
#define OFF_SUMS_T   443392u     // float [NB*NC*NCLS]        311296 B
#define OFF_NORM_S   754688u     // float [NB*NCLS]           (padded 1024)
#define OFF_NORM_T   755712u     // float [NB*NCLS]           (padded 1024)
#define OFF_DOT_S    756736u     // float [NB*NHW]            131072 B
#define OFF_NRM_S    887808u
#define OFF_DOT_T    1018880u
#define OFF_NRM_T    1149952u
// total ~1.28 MB

// ---------------------------------------------------------------------------
// Kernel 1: nearest-resize labels (512x512 -> 64x64) + per-batch class counts
__global__ __launch_bounds__(256) void k_labels(const int* __restrict__ target,
                                                int* __restrict__ labels,
                                                float* __restrict__ counts) {
    __shared__ int hist[NCLS];
    const int b = blockIdx.x;
    const int t = threadIdx.x;
    if (t < NCLS) hist[t] = 0;
    __syncthreads();
    const int* tb = target + (size_t)b * 512 * 512;
    #pragma unroll
    for (int i = 0; i < 16; ++i) {
        int n = t + i * 256;
        int y = n >> 6, x = n & 63;
        int l = tb[(y * 8) * 512 + x * 8];   // in_idx = floor(out_idx*512/64) = 8*out_idx
        labels[b * NHW + n] = l;
        if (l >= 0 && l < NCLS) atomicAdd(&hist[l], 1);
    }
    __syncthreads();
    if (t < NCLS) counts[b * NCLS + t] = (float)hist[t];
}

// ---------------------------------------------------------------------------
// Kernel 2: per-(b,c) class sums for both tensors.
// One block per (b,c). Per-thread LDS buckets, layout [row][t] with row =
// class (S: 0..18, T: 19..37) so lane->bank is 2-way aliased only (free).
__global__ __launch_bounds__(256) void k_sums(const float* __restrict__ fS,
                                              const float* __restrict__ fT,
                                              const int* __restrict__ labels,
                                              float* __restrict__ sumsS,
                                              float* __restrict__ sumsT) {
    __shared__ float buck[2 * NCLS * 256];   // 38912 B
    const int bc = blockIdx.x;               // b*512 + c
    const int b = bc >> 9;
    const int t = threadIdx.x;
    for (int r = t; r < 2 * NCLS * 256; r += 256) buck[r] = 0.f;
    __syncthreads();
    const float* pS = fS + (size_t)bc * NHW;
    const float* pT = fT + (size_t)bc * NHW;
    const int* lab = labels + b * NHW;
    #pragma unroll
    for (int i = 0; i < 16; ++i) {
        int n = t + i * 256;
        int l = lab[n];
        if (l >= 0 && l < NCLS) {
            buck[l * 256 + t]          += pS[n];
            buck[(NCLS + l) * 256 + t] += pT[n];
        }
    }
    __syncthreads();
    // Flat tree-reduce each of the 38 rows over t (column-parallel).
    for (int sh = 7; sh >= 0; --sh) {
        const int s = 1 << sh;
        for (int idx = t; idx < 2 * NCLS * s; idx += 256) {
            int r = idx >> sh, tt = idx & (s - 1);
            buck[r * 256 + tt] += buck[r * 256 + tt + s];
        }
        __syncthreads();
    }
    if (t < NCLS)           sumsS[(size_t)bc * NCLS + t]          = buck[t * 256];
    else if (t < 2 * NCLS)  sumsT[(size_t)bc * NCLS + (t - NCLS)] = buck[t * 256];
}

// ---------------------------------------------------------------------------
// Kernel 3: means = sums/(counts+eps) in place, plus per-(b,k) center norms.
// One block (64 threads = 1 wave) per (b,k); handles both tensors.
__global__ __launch_bounds__(64) void k_means(float* __restrict__ sumsS,
                                              float* __restrict__ sumsT,
                                              const float* __restrict__ counts,
                                              float* __restrict__ normS,
                                              float* __restrict__ normT) {
    const int bk = blockIdx.x;        // b*19 + k
    const int b = bk / NCLS;
    const int k = bk - b * NCLS;
    const int t = threadIdx.x;
    const float inv = 1.f / (counts[bk] + EPSM);
    float accS = 0.f, accT = 0.f;
    #pragma unroll
    for (int ci = 0; ci < NC / 64; ++ci) {
        int c = t + ci * 64;
        size_t idx = ((size_t)(b * NC + c)) * NCLS + k;
        float mS = sumsS[idx] * inv; sumsS[idx] = mS; accS += mS * mS;
        float mT = sumsT[idx] * inv; sumsT[idx] = mT; accT += mT * mT;
    }
    #pragma unroll
    for (int off = 32; off > 0; off >>= 1) {
        accS += __shfl_down(accS, off, 64);
        accT += __shfl_down(accT, off, 64);
    }
    if (t == 0) { normS[bk] = sqrtf(accS); normT[bk] = sqrtf(accT); }
}

// ---------------------------------------------------------------------------
// Kernel 4: per-pixel dot(f, mean[lab]) and ||f||^2, c-chunked.
// Grid: b(8) x pixel-tile(16 of 256) x chunk(8 of 64 channels) = 1024 blocks.
// Means tile is contiguous [c][k] in global -> straight LDS copy; gather by
// label hits 19 consecutive words (distinct banks / broadcast) -> conflict-free.
#define CCHUNK 64
__global__ __launch_bounds__(256) void k_dots(const float* __restrict__ fS,
                                              const float* __restrict__ fT,
                                              const float* __restrict__ meansS,
                                              const float* __restrict__ meansT,
                                              const int* __restrict__ labels,
                                              float* __restrict__ dotS,
                                              float* __restrict__ nrmS,
                                              float* __restrict__ dotT,
                                              float* __restrict__ nrmT) {
    __shared__ float mS[CCHUNK * NCLS];   // 4864 B
    __shared__ float mT[CCHUNK * NCLS];
    const int blk = blockIdx.x;
    const int chunk = blk & 7;
    const int tile  = (blk >> 3) & 15;
    const int b     = blk >> 7;
    const int t = threadIdx.x;
    const int c0 = chunk * CCHUNK;
    const int n = tile * 256 + t;

    const float* srcS = meansS + ((size_t)(b * NC + c0)) * NCLS;
    const float* srcT = meansT + ((size_t)(b * NC + c0)) * NCLS;
    for (int i = t; i < CCHUNK * NCLS; i += 256) { mS[i] = srcS[i]; mT[i] = srcT[i]; }
    __syncthreads();

    const int l = labels[b * NHW + n];
    const int lc = (l >= 0 && l < NCLS) ? l : 0;   // safe index; invalid handled in k_final
    const float* pS = fS + ((size_t)(b * NC + c0)) * NHW + n;
    const float* pT = fT + ((size_t)(b * NC + c0)) * NHW + n;
    float dS = 0.f, nS = 0.f, dT = 0.f, nT = 0.f;
    #pragma unroll 8
    for (int ci = 0; ci < CCHUNK; ++ci) {
        float vS = pS[(size_t)ci * NHW];
        float vT = pT[(size_t)ci * NHW];
        float ms = mS[ci * NCLS + lc];
        float mt = mT[ci * NCLS + lc];
        dS += vS * ms; nS += vS * vS;
        dT += vT * mt; nT += vT * vT;
    }
    const size_t p = (size_t)b * NHW + n;
    atomicAdd(&dotS[p], dS);
    atomicAdd(&nrmS[p], nS);
    atomicAdd(&dotT[p], dT);
    atomicAdd(&nrmT[p], nT);
}

// ---------------------------------------------------------------------------
// Kernel 5: cosines, squared diff, mean-reduce into d_out.
__global__ __launch_bounds__(256) void k_final(const float* __restrict__ dotS,
                                               const float* __restrict__ nrmS,
                                               const float* __restrict__ dotT,
                                               const float* __restrict__ nrmT,
                                               const int* __restrict__ labels,
                                               const float* __restrict__ normS,
                                               const float* __restrict__ normT,
                                               float* __restrict__ out) {
    __shared__ float red[256];
    const int p = blockIdx.x * 256 + threadIdx.x;
    const int b = p >> 12;
    const int l = labels[p];
    float val = 0.f;
    if (l >= 0 && l < NCLS) {
        float cS = dotS[p] / (fmaxf(sqrtf(nrmS[p]), EPSC) * fmaxf(normS[b * NCLS + l], EPSC));
        float cT = dotT[p] / (fmaxf(sqrtf(nrmT[p]), EPSC) * fmaxf(normT[b * NCLS + l], EPSC));
        float d = cS - cT;
        val = d * d;
    }
    // invalid label => center = f itself => cos==cos => contributes 0 (handled)
    red[threadIdx.x] = val;
    __syncthreads();
    for (int s = 128; s > 0; s >>= 1) {
        if (threadIdx.x < s) red[threadIdx.x] += red[threadIdx.x + s];
        __syncthreads();
    }
    if (threadIdx.x == 0) atomicAdd(out, red[0] * (1.0f / (NB * NHW)));
}

// ---------------------------------------------------------------------------
extern "C" void kernel_launch(void* const* d_in, const int* in_sizes, int n_in,
                              void* d_out, int out_size, void* d_ws, size_t ws_size,
                              hipStream_t stream) {
    (void)in_sizes; (void)n_in; (void)out_size; (void)ws_size;
    const float* fS     = (const float*)d_in[0];
    const float* fT     = (const float*)d_in[1];
    const int*   target = (const int*)d_in[2];

    char* ws = (char*)d_ws;
    int*   labels = (int*)  (ws + OFF_LABELS);
    float* counts = (float*)(ws + OFF_COUNTS);
    float* sumsS  = (float*)(ws + OFF_SUMS_S);   // becomes meansS in place
    float* sumsT  = (float*)(ws + OFF_SUMS_T);   // becomes meansT in place
    float* normS  = (float*)(ws + OFF_NORM_S);
    float* normT  = (float*)(ws + OFF_NORM_T);
    float* dotS   = (float*)(ws + OFF_DOT_S);
    float* nrmS   = (float*)(ws + OFF_NRM_S);
    float* dotT   = (float*)(ws + OFF_DOT_T);
    float* nrmT   = (float*)(ws + OFF_NRM_T);

    // Zero accumulators (ws/d_out are poisoned 0xAA before every timed call)
    hipMemsetAsync(d_out, 0, sizeof(float), stream);
    hipMemsetAsync(ws + OFF_DOT_S, 0, 4u * NB * NHW * sizeof(float), stream);

    k_labels<<<NB, 256, 0, stream>>>(target, labels, counts);
    k_sums  <<<NB * NC, 256, 0, stream>>>(fS, fT, labels, sumsS, sumsT);
    k_means <<<NB * NCLS, 64, 0, stream>>>(sumsS, sumsT, counts, normS, normT);
    k_dots  <<<NB * 16 * 8, 256, 0, stream>>>(fS, fT, sumsS, sumsT, labels,
                                              dotS, nrmS, dotT, nrmT);
    k_final <<<NB * NHW / 256, 256, 0, stream>>>(dotS, nrmS, dotT, nrmT, labels,
                                                 normS, normT, (float*)d_out);
}

// Round 2
// 211.675 us; speedup vs baseline: 1.1533x; 1.1533x over previous
//
#include <hip/hip_runtime.h>

// Problem constants (B=8, C=512, H=W=64, K=19 classes)
#define NCLS   19
#define NB     8
#define NC     512
#define NHW    4096      // 64*64
#define EPSM   1e-6f     // mean denominator eps
#define EPSC   1e-8f     // cosine eps

// Workspace layout (bytes)
#define OFF_LABELS   0u          // int32 [NB*NHW]
#define OFF_COUNTS   131072u     // float [NB*NCLS] ([b][k])
#define OFF_SUMS_S   132096u     // float [NB][NCLS][NC]  (becomes means in place)
#define OFF_SUMS_T   443392u     // float [NB][NCLS][NC]
#define OFF_NORM_S   754688u     // float [NB*NCLS]
#define OFF_NORM_T   755712u     // float [NB*NCLS]
#define OFF_PART     756736u     // float [4 arrays][8 chunks][NB*NHW]
// total = 756736 + 4*8*32768*4 = 4,951,040 B

// ---------------------------------------------------------------------------
// Wave-64 sum via DPP (VALU pipe only, no LDS). Result valid in lane 63.
template<int CTRL>
__device__ __forceinline__ float dpp_add(float x) {
    int y = __builtin_amdgcn_update_dpp(0, __float_as_int(x), CTRL, 0xf, 0xf, false);
    return x + __int_as_float(y);
}
__device__ __forceinline__ float wave64_sum(float x) {
    x = dpp_add<0x111>(x);   // row_shr:1
    x = dpp_add<0x112>(x);   // row_shr:2
    x = dpp_add<0x114>(x);   // row_shr:4
    x = dpp_add<0x118>(x);   // row_shr:8  -> lane15 of each row16 has row sum
    x = dpp_add<0x142>(x);   // row_bcast:15 -> lane31/63 have half sums
    x = dpp_add<0x143>(x);   // row_bcast:31 -> lane63 has total
    return x;
}

// ---------------------------------------------------------------------------
// Kernel 1: nearest-resize labels (512x512 -> 64x64) + per-batch class counts
__global__ __launch_bounds__(256) void k_labels(const int* __restrict__ target,
                                                int* __restrict__ labels,
                                                float* __restrict__ counts) {
    __shared__ int hist[NCLS];
    const int b = blockIdx.x;
    const int t = threadIdx.x;
    if (t < NCLS) hist[t] = 0;
    __syncthreads();
    const int* tb = target + (size_t)b * 512 * 512;
    #pragma unroll
    for (int i = 0; i < 16; ++i) {
        int n = t + i * 256;
        int y = n >> 6, x = n & 63;
        int l = tb[(y * 8) * 512 + x * 8];   // in_idx = floor(out_idx*512/64)
        labels[b * NHW + n] = l;
        if (l >= 0 && l < NCLS) atomicAdd(&hist[l], 1);
    }
    __syncthreads();
    if (t < NCLS) counts[b * NCLS + t] = (float)hist[t];
}

// ---------------------------------------------------------------------------
// Kernel 2: per-class channel sums, register-resident compare-select.
// Each WAVE owns 2 channels (S and T): 76 register accumulators/thread.
// Grid: 512 blocks x 256 thr = 2048 waves = 8 b x 256 channel-pairs.
// Output layout: sums[b][k][c] (k-major) for coalesced downstream reads.
__global__ __launch_bounds__(256, 2) void k_sums(const float* __restrict__ fS,
                                                 const float* __restrict__ fT,
                                                 const int* __restrict__ labels,
                                                 float* __restrict__ sumsS,
                                                 float* __restrict__ sumsT) {
    const int t = threadIdx.x;
    const int lane = t & 63;
    const int u = (blockIdx.x << 2) + (t >> 6);   // wave-unit 0..2047
    const int b = u >> 8;
    const int c0 = (u & 255) << 1;                // channels c0, c0+1
    const size_t base = ((size_t)(b * NC) + c0) * NHW;
    const float4* pS0 = (const float4*)(fS + base);
    const float4* pS1 = (const float4*)(fS + base + NHW);
    const float4* pT0 = (const float4*)(fT + base);
    const float4* pT1 = (const float4*)(fT + base + NHW);
    const int4* lab4 = (const int4*)(labels + b * NHW);

    float aS0[NCLS], aS1[NCLS], aT0[NCLS], aT1[NCLS];
    #pragma unroll
    for (int k = 0; k < NCLS; ++k) { aS0[k] = aS1[k] = aT0[k] = aT1[k] = 0.f; }

    #pragma unroll 2
    for (int i = 0; i < 16; ++i) {
        const int idx = lane + (i << 6);          // float4 index (4 pixels)
        const float4 vS0 = pS0[idx];
        const float4 vS1 = pS1[idx];
        const float4 vT0 = pT0[idx];
        const float4 vT1 = pT1[idx];
        const int4 l4 = lab4[idx];
        #pragma unroll
        for (int k = 0; k < NCLS; ++k) {
            const float m0 = (l4.x == k) ? 1.f : 0.f;
            const float m1 = (l4.y == k) ? 1.f : 0.f;
            const float m2 = (l4.z == k) ? 1.f : 0.f;
            const float m3 = (l4.w == k) ? 1.f : 0.f;
            aS0[k] += m0 * vS0.x + m1 * vS0.y + m2 * vS0.z + m3 * vS0.w;
            aS1[k] += m0 * vS1.x + m1 * vS1.y + m2 * vS1.z + m3 * vS1.w;
            aT0[k] += m0 * vT0.x + m1 * vT0.y + m2 * vT0.z + m3 * vT0.w;
            aT1[k] += m0 * vT1.x + m1 * vT1.y + m2 * vT1.z + m3 * vT1.w;
        }
    }
    // Cross-lane reduce each accumulator (DPP, lane 63 holds totals)
    #pragma unroll
    for (int k = 0; k < NCLS; ++k) {
        aS0[k] = wave64_sum(aS0[k]);
        aS1[k] = wave64_sum(aS1[k]);
        aT0[k] = wave64_sum(aT0[k]);
        aT1[k] = wave64_sum(aT1[k]);
    }
    if (lane == 63) {
        #pragma unroll
        for (int k = 0; k < NCLS; ++k) {
            float2* dS = (float2*)(sumsS + ((size_t)(b * NCLS + k)) * NC + c0);
            float2* dT = (float2*)(sumsT + ((size_t)(b * NCLS + k)) * NC + c0);
            *dS = make_float2(aS0[k], aS1[k]);
            *dT = make_float2(aT0[k], aT1[k]);
        }
    }
}

// ---------------------------------------------------------------------------
// Kernel 3: means = sums/(count+eps) in place + per-(b,k) center norms.
// One wave per (b,k); sums layout [b][k][c] -> coalesced.
__global__ __launch_bounds__(64) void k_means(float* __restrict__ sumsS,
                                              float* __restrict__ sumsT,
                                              const float* __restrict__ counts,
                                              float* __restrict__ normS,
                                              float* __restrict__ normT) {
    const int bk = blockIdx.x;
    const int t = threadIdx.x;
    const float inv = 1.f / (counts[bk] + EPSM);
    float* rS = sumsS + (size_t)bk * NC;
    float* rT = sumsT + (size_t)bk * NC;
    float aS = 0.f, aT = 0.f;
    #pragma unroll
    for (int i = 0; i < NC / 64; ++i) {
        float mS = rS[t + i * 64] * inv; rS[t + i * 64] = mS; aS += mS * mS;
        float mT = rT[t + i * 64] * inv; rT[t + i * 64] = mT; aT += mT * mT;
    }
    aS = wave64_sum(aS);
    aT = wave64_sum(aT);
    if (t == 63) { normS[bk] = sqrtf(aS); normT[bk] = sqrtf(aT); }
}

// ---------------------------------------------------------------------------
// Kernel 4: per-pixel dot(f, mean[lab]) and ||f||^2, atomic-free.
// Grid: 8 b x 16 pixel-tiles x 8 c-chunks = 1024 blocks.
// Means tile in LDS as [class][65] -> gather bank = (l+ci)%32, conflict-free.
#define CCH 64
__global__ __launch_bounds__(256) void k_dots(const float* __restrict__ fS,
                                              const float* __restrict__ fT,
                                              const float* __restrict__ meansS,
                                              const float* __restrict__ meansT,
                                              const int* __restrict__ labels,
                                              float* __restrict__ part) {
    __shared__ float mS[NCLS * 65];
    __shared__ float mT[NCLS * 65];
    const int blk = blockIdx.x;
    const int chunk = blk & 7;
    const int tile  = (blk >> 3) & 15;
    const int b     = blk >> 7;
    const int t = threadIdx.x;
    const int c0 = chunk * CCH;
    const int n = tile * 256 + t;

    for (int i = t; i < NCLS * CCH; i += 256) {
        const int k = i >> 6, j = i & 63;
        mS[k * 65 + j] = meansS[((size_t)(b * NCLS + k)) * NC + c0 + j];
        mT[k * 65 + j] = meansT[((size_t)(b * NCLS + k)) * NC + c0 + j];
    }
    __syncthreads();

    const int l = labels[b * NHW + n];
    const int lc = (l >= 0 && l < NCLS) ? l : 0;
    const float* pS = fS + ((size_t)(b * NC + c0)) * NHW + n;
    const float* pT = fT + ((size_t)(b * NC + c0)) * NHW + n;
    float dS = 0.f, nS = 0.f, dT = 0.f, nT = 0.f;
    #pragma unroll 8
    for (int ci = 0; ci < CCH; ++ci) {
        const float vS = pS[(size_t)ci * NHW];
        const float vT = pT[(size_t)ci * NHW];
        const float ms = mS[lc * 65 + ci];
        const float mt = mT[lc * 65 + ci];
        dS += vS * ms; nS += vS * vS;
        dT += vT * mt; nT += vT * vT;
    }
    const int p = b * NHW + n;
    part[((size_t)(0 * 8 + chunk)) * (NB * NHW) + p] = dS;
    part[((size_t)(1 * 8 + chunk)) * (NB * NHW) + p] = nS;
    part[((size_t)(2 * 8 + chunk)) * (NB * NHW) + p] = dT;
    part[((size_t)(3 * 8 + chunk)) * (NB * NHW) + p] = nT;
}

// ---------------------------------------------------------------------------
// Kernel 5: combine partials, cosines, MSE reduce.
__global__ __launch_bounds__(256) void k_final(const float* __restrict__ part,
                                               const int* __restrict__ labels,
                                               const float* __restrict__ normS,
                                               const float* __restrict__ normT,
                                               float* __restrict__ out) {
    __shared__ float red[4];
    const int p = blockIdx.x * 256 + threadIdx.x;
    const int b = p >> 12;
    float dS = 0.f, nS = 0.f, dT = 0.f, nT = 0.f;
    #pragma unroll
    for (int ch = 0; ch < 8; ++ch) {
        dS += part[((size_t)(0 * 8 + ch)) * (NB * NHW) + p];
        nS += part[((size_t)(1 * 8 + ch)) * (NB * NHW) + p];
        dT += part[((size_t)(2 * 8 + ch)) * (NB * NHW) + p];
        nT += part[((size_t)(3 * 8 + ch)) * (NB * NHW) + p];
    }
    const int l = labels[p];
    float val = 0.f;
    if (l >= 0 && l < NCLS) {
        float cS = dS / (fmaxf(sqrtf(nS), EPSC) * fmaxf(normS[b * NCLS + l], EPSC));
        float cT = dT / (fmaxf(sqrtf(nT), EPSC) * fmaxf(normT[b * NCLS + l], EPSC));
        float d = cS - cT;
        val = d * d;
    }
    val = wave64_sum(val);
    if ((threadIdx.x & 63) == 63) red[threadIdx.x >> 6] = val;
    __syncthreads();
    if (threadIdx.x == 0)
        atomicAdd(out, (red[0] + red[1] + red[2] + red[3]) * (1.f / (NB * NHW)));
}

// ---------------------------------------------------------------------------
extern "C" void kernel_launch(void* const* d_in, const int* in_sizes, int n_in,
                              void* d_out, int out_size, void* d_ws, size_t ws_size,
                              hipStream_t stream) {
    (void)in_sizes; (void)n_in; (void)out_size; (void)ws_size;
    const float* fS     = (const float*)d_in[0];
    const float* fT     = (const float*)d_in[1];
    const int*   target = (const int*)d_in[2];

    char* ws = (char*)d_ws;
    int*   labels = (int*)  (ws + OFF_LABELS);
    float* counts = (float*)(ws + OFF_COUNTS);
    float* sumsS  = (float*)(ws + OFF_SUMS_S);
    float* sumsT  = (float*)(ws + OFF_SUMS_T);
    float* normS  = (float*)(ws + OFF_NORM_S);
    float* normT  = (float*)(ws + OFF_NORM_T);
    float* part   = (float*)(ws + OFF_PART);

    hipMemsetAsync(d_out, 0, sizeof(float), stream);

    k_labels<<<NB, 256, 0, stream>>>(target, labels, counts);
    k_sums  <<<NB * NC / 8, 256, 0, stream>>>(fS, fT, labels, sumsS, sumsT);
    k_means <<<NB * NCLS, 64, 0, stream>>>(sumsS, sumsT, counts, normS, normT);
    k_dots  <<<NB * 16 * 8, 256, 0, stream>>>(fS, fT, sumsS, sumsT, labels, part);
    k_final <<<NB * NHW / 256, 256, 0, stream>>>(part, labels, normS, normT,
                                                 (float*)d_out);
}